// Round 1
// baseline (571.635 us; speedup 1.0000x reference)
//
#include <hip/hip_runtime.h>
#include <math.h>

#define B_Q 1024
#define L_SEQ 128
#define D_EMB 256
#define NLAB 131072
#define LBL_ROWS 8192
#define NEG_ROWS 2048
#define W_ROWS 10240
#define CROW 320   // compact row: 64 poly + 256 prf

__device__ __forceinline__ float wave_sum(float v) {
#pragma unroll
  for (int off = 32; off > 0; off >>= 1) v += __shfl_xor(v, off, 64);
  return v;
}

// sx: 256 per-head-normalized input dims in LDS. t in [0,256).
// Writes one compact row: [0,64) = poly_feat[h*16+p], [64,320) = prf_feat[r*128+h*32+m]
__device__ __forceinline__ void slay_tail(const float* __restrict__ sx, int t,
                                          const float* __restrict__ anchT,
                                          const float* __restrict__ omega,
                                          float* __restrict__ outrow) {
  if (t < 64) {
    const int h = t >> 4, p = t & 15;
    const float* x = sx + h * 64;
    float d = 0.f;
#pragma unroll
    for (int dd = 0; dd < 64; dd++) d = fmaf(x[dd], anchT[dd * 16 + p], d);
    d = fminf(fmaxf(d, -1.0f), 1.0f);
    outrow[h * 16 + p] = d * d * 0.25f;   // proj^2 / sqrt(16)
  }
  {
    const int r = t >> 7, h = (t >> 5) & 3;
    const float* x = sx + h * 64;
    const float* om = omega + (size_t)(t >> 5) * 2048 + (t & 31); // ((r*4+h)*64+dd)*32+m
    float d = 0.f;
#pragma unroll
    for (int dd = 0; dd < 64; dd++) d = fmaf(x[dd], om[dd * 32], d);
    const float proj = d * 0.125f;  // omega_n = omega / sqrt(64)
    // QUAD_NODES/WEIGHTS (laggauss(2), max(.,0.01)/2.000001), float32 of exact doubles
    const float s = r ? 1.70710592763316f : 0.29289307236691f;
    const float w = r ? 0.07322326809171f : 0.42677648190829f;
    float arg = proj * sqrtf(2.0f * s) - s;
    arg = fminf(fmaxf(arg, -20.0f), 20.0f);
    outrow[64 + t] = expf(arg) * (sqrtf(w) / sqrtf(32.000001f));
  }
}

// anchors (16x64) -> normalized, transposed: anchT[d*16+p]
__global__ void k_anchors(const float* __restrict__ anchors, float* __restrict__ anchT) {
  const int d = threadIdx.x;  // 64 threads = 1 wave
  for (int p = 0; p < 16; p++) {
    const float v = anchors[p * 64 + d];
    const float n = sqrtf(wave_sum(v * v));
    anchT[d * 16 + p] = v / n;   // reference: plain divide, no eps
  }
}

__global__ __launch_bounds__(256) void k_query(const int* __restrict__ indices,
                                               const float* __restrict__ mask,
                                               const float* __restrict__ embed,
                                               const float* __restrict__ anchT,
                                               const float* __restrict__ omega,
                                               float* __restrict__ qcomp) {
  const int b = blockIdx.x, t = threadIdx.x;
  __shared__ int sidx[L_SEQ];
  __shared__ float smask[L_SEQ];
  __shared__ float sx[256];
  if (t < L_SEQ) { sidx[t] = indices[b * L_SEQ + t]; smask[t] = mask[b * L_SEQ + t]; }
  __syncthreads();
  float acc = 0.f, msum = 0.f;
  for (int l = 0; l < L_SEQ; l++) {
    const float m = smask[l];
    msum += m;
    acc = fmaf(embed[(size_t)sidx[l] * D_EMB + t], m, acc);
  }
  const float q = acc / fmaxf(msum, 1.0f);
  // full-vector safe_normalize is a no-op before per-head normalize (norm >> eps)
  const float ss = wave_sum(q * q);   // wave == head (64 dims)
  sx[t] = q / fmaxf(sqrtf(ss), 1e-4f);
  __syncthreads();
  slay_tail(sx, t, anchT, omega, qcomp + (size_t)b * CROW);
}

__global__ __launch_bounds__(256) void k_wrows(const int* __restrict__ labels,
                                               const int* __restrict__ negidx,
                                               const float* __restrict__ kern,
                                               const float* __restrict__ anchT,
                                               const float* __restrict__ omega,
                                               float* __restrict__ wcomp) {
  const int i = blockIdx.x, t = threadIdx.x;
  __shared__ float sx[256];
  int j;
  if (i < LBL_ROWS) { j = labels[i]; if (j < 0) j = 0; }
  else               { j = negidx[i - LBL_ROWS]; }
  const float x = kern[(size_t)t * NLAB + j];   // W[j][t] = kernel[t][j]
  const float ss = wave_sum(x * x);
  sx[t] = x / fmaxf(sqrtf(ss), 1e-4f);
  __syncthreads();
  slay_tail(sx, t, anchT, omega, wcomp + (size_t)i * CROW);
}

// neg partial sums: grid (64 qtiles, 8 chunks), 128 threads.
// Block: 16 queries x 256 neg rows. Thread: 4q x 4w x one h.
#define LSTR 321
__global__ __launch_bounds__(128) void k_neg(const float* __restrict__ qcomp,
                                             const float* __restrict__ wcomp,
                                             float* __restrict__ negparts) {
  __shared__ float qt[16 * LSTR];
  __shared__ float wt[32 * LSTR];
  __shared__ float accs[16];
  const int tid = threadIdx.x;
  const int qb0 = blockIdx.x * 16;
  const int wrow0 = LBL_ROWS + blockIdx.y * 256;

  for (int r = 0; r < 16; r++)
    for (int c = tid; c < CROW; c += 128)
      qt[r * LSTR + c] = qcomp[(size_t)(qb0 + r) * CROW + c];
  if (tid < 16) accs[tid] = 0.f;

  const int wg = tid & 7, h = (tid >> 3) & 3, qg = tid >> 5;
  const int po = h * 16, fo0 = 64 + h * 32, fo1 = 192 + h * 32;
  float negacc[4] = {0.f, 0.f, 0.f, 0.f};

  for (int st = 0; st < 8; st++) {
    __syncthreads();
    for (int r = 0; r < 32; r++)
      for (int c = tid; c < CROW; c += 128)
        wt[r * LSTR + c] = wcomp[(size_t)(wrow0 + st * 32 + r) * CROW + c];
    __syncthreads();

    const float* qp[4];
    const float* wp[4];
#pragma unroll
    for (int i = 0; i < 4; i++) qp[i] = qt + (qg * 4 + i) * LSTR;
#pragma unroll
    for (int j = 0; j < 4; j++) wp[j] = wt + (wg * 4 + j) * LSTR;

    float pd[4][4], pfa[4][4], pfb[4][4];
#pragma unroll
    for (int i = 0; i < 4; i++)
#pragma unroll
      for (int j = 0; j < 4; j++) { pd[i][j] = 0.f; pfa[i][j] = 0.f; pfb[i][j] = 0.f; }

#pragma unroll
    for (int p = 0; p < 16; p++) {
      float qv[4], wv[4];
#pragma unroll
      for (int i = 0; i < 4; i++) qv[i] = qp[i][po + p];
#pragma unroll
      for (int j = 0; j < 4; j++) wv[j] = wp[j][po + p];
#pragma unroll
      for (int i = 0; i < 4; i++)
#pragma unroll
        for (int j = 0; j < 4; j++) pd[i][j] = fmaf(qv[i], wv[j], pd[i][j]);
    }
#pragma unroll
    for (int m = 0; m < 32; m++) {
      float qv[4], wv[4];
#pragma unroll
      for (int i = 0; i < 4; i++) qv[i] = qp[i][fo0 + m];
#pragma unroll
      for (int j = 0; j < 4; j++) wv[j] = wp[j][fo0 + m];
#pragma unroll
      for (int i = 0; i < 4; i++)
#pragma unroll
        for (int j = 0; j < 4; j++) pfa[i][j] = fmaf(qv[i], wv[j], pfa[i][j]);
    }
#pragma unroll
    for (int m = 0; m < 32; m++) {
      float qv[4], wv[4];
#pragma unroll
      for (int i = 0; i < 4; i++) qv[i] = qp[i][fo1 + m];
#pragma unroll
      for (int j = 0; j < 4; j++) wv[j] = wp[j][fo1 + m];
#pragma unroll
      for (int i = 0; i < 4; i++)
#pragma unroll
        for (int j = 0; j < 4; j++) pfb[i][j] = fmaf(qv[i], wv[j], pfb[i][j]);
    }
#pragma unroll
    for (int i = 0; i < 4; i++) {
      float sacc = 0.f;
#pragma unroll
      for (int j = 0; j < 4; j++) sacc += pd[i][j] * (pfa[i][j] + pfb[i][j]);
      negacc[i] += sacc;
    }
  }
#pragma unroll
  for (int i = 0; i < 4; i++) atomicAdd(&accs[qg * 4 + i], negacc[i]);
  __syncthreads();
  if (tid < 16) negparts[(size_t)(qb0 + tid) * 8 + blockIdx.y] = accs[tid];
}

__global__ __launch_bounds__(128) void k_pos(const float* __restrict__ qcomp,
                                             const float* __restrict__ wcomp,
                                             float* __restrict__ pos) {
  const int g = blockIdx.x * 128 + threadIdx.x;  // 8192
  const float* q = qcomp + (size_t)(g >> 3) * CROW;
  const float* w = wcomp + (size_t)g * CROW;
  float score = 0.f;
#pragma unroll
  for (int h = 0; h < 4; h++) {
    float pd = 0.f, p0 = 0.f, p1 = 0.f;
#pragma unroll
    for (int p = 0; p < 16; p++) pd = fmaf(q[h * 16 + p], w[h * 16 + p], pd);
#pragma unroll
    for (int m = 0; m < 32; m++) p0 = fmaf(q[64 + h * 32 + m], w[64 + h * 32 + m], p0);
#pragma unroll
    for (int m = 0; m < 32; m++) p1 = fmaf(q[192 + h * 32 + m], w[192 + h * 32 + m], p1);
    score += pd * (p0 + p1);
  }
  pos[g] = score;
}

__global__ __launch_bounds__(1024) void k_loss(const float* __restrict__ pos,
                                               const float* __restrict__ negparts,
                                               const float* __restrict__ lmask,
                                               float* __restrict__ out) {
  const int b = threadIdx.x;  // 1024
  float lp[8];
  float possum = 0.f;
#pragma unroll
  for (int k = 0; k < 8; k++) { lp[k] = pos[b * 8 + k]; possum += lp[k]; }
  float negsum = 0.f;
#pragma unroll
  for (int c = 0; c < 8; c++) negsum += negparts[b * 8 + c];
  const float Z = possum + negsum + 2.056e-5f;  // + 2056 * 1e-8
  const float logZ = logf(Z);
  float local = 0.f, lsum = 0.f;
#pragma unroll
  for (int k = 0; k < 8; k++) {
    const float lm = lmask[b * 8 + k];
    local += lm * (logf(lp[k] + 1e-8f) - logZ);
    lsum += lm;
  }
  local = wave_sum(local);
  lsum = wave_sum(lsum);
  __shared__ float r1[16], r2[16];
  const int wid = b >> 6;
  if ((b & 63) == 0) { r1[wid] = local; r2[wid] = lsum; }
  __syncthreads();
  if (b == 0) {
    float t1 = 0.f, t2 = 0.f;
    for (int wv = 0; wv < 16; wv++) { t1 += r1[wv]; t2 += r2[wv]; }
    out[0] = -t1 / (t2 + 1e-6f);
  }
}

extern "C" void kernel_launch(void* const* d_in, const int* in_sizes, int n_in,
                              void* d_out, int out_size, void* d_ws, size_t ws_size,
                              hipStream_t stream) {
  const int* indices  = (const int*)d_in[0];
  const float* mask   = (const float*)d_in[1];
  const int* labels   = (const int*)d_in[2];
  const float* lmask  = (const float*)d_in[3];
  const int* negidx   = (const int*)d_in[4];
  const float* embed  = (const float*)d_in[5];
  const float* kern   = (const float*)d_in[6];
  const float* omega  = (const float*)d_in[7];
  const float* anchors= (const float*)d_in[8];
  float* out = (float*)d_out;

  float* ws = (float*)d_ws;
  float* anchT    = ws;                         // 1024
  float* qcomp    = anchT + 1024;               // 1024*320
  float* wcomp    = qcomp + (size_t)B_Q * CROW; // 10240*320
  float* pos      = wcomp + (size_t)W_ROWS * CROW; // 8192
  float* negparts = pos + LBL_ROWS;             // 1024*8

  k_anchors<<<1, 64, 0, stream>>>(anchors, anchT);
  k_query<<<B_Q, 256, 0, stream>>>(indices, mask, embed, anchT, omega, qcomp);
  k_wrows<<<W_ROWS, 256, 0, stream>>>(labels, negidx, kern, anchT, omega, wcomp);
  k_neg<<<dim3(64, 8), 128, 0, stream>>>(qcomp, wcomp, negparts);
  k_pos<<<64, 128, 0, stream>>>(qcomp, wcomp, pos);
  k_loss<<<1, 1024, 0, stream>>>(pos, negparts, lmask, out);
}

// Round 2
// 366.284 us; speedup vs baseline: 1.5606x; 1.5606x over previous
//
#include <hip/hip_runtime.h>
#include <math.h>

#define B_Q 1024
#define L_SEQ 128
#define D_EMB 256
#define NLAB 131072
#define LBL_ROWS 8192
#define NEG_ROWS 2048
#define W_ROWS 10240
#define CROW 320   // compact row: 64 poly + 256 prf
#define LST 82     // k_neg LDS row stride (floats): rows 4 apart -> 8 banks apart

__device__ __forceinline__ float wave_sum(float v) {
#pragma unroll
  for (int off = 32; off > 0; off >>= 1) v += __shfl_xor(v, off, 64);
  return v;
}

// sx: 256 per-head-normalized input dims in LDS. t in [0,256).
// Writes one compact row: [0,64) = poly_feat[h*16+p], [64,320) = prf_feat[r*128+h*32+m]
__device__ __forceinline__ void slay_tail(const float* __restrict__ sx, int t,
                                          const float* __restrict__ anchT,
                                          const float* __restrict__ omega,
                                          float* __restrict__ outrow) {
  if (t < 64) {
    const int h = t >> 4, p = t & 15;
    const float* x = sx + h * 64;
    float d = 0.f;
#pragma unroll
    for (int dd = 0; dd < 64; dd++) d = fmaf(x[dd], anchT[dd * 16 + p], d);
    d = fminf(fmaxf(d, -1.0f), 1.0f);
    outrow[h * 16 + p] = d * d * 0.25f;   // proj^2 / sqrt(16)
  }
  {
    const int r = t >> 7, h = (t >> 5) & 3;
    const float* x = sx + h * 64;
    const float* om = omega + (size_t)(t >> 5) * 2048 + (t & 31); // ((r*4+h)*64+dd)*32+m
    float d = 0.f;
#pragma unroll
    for (int dd = 0; dd < 64; dd++) d = fmaf(x[dd], om[dd * 32], d);
    const float proj = d * 0.125f;  // omega_n = omega / sqrt(64)
    const float s = r ? 1.70710592763316f : 0.29289307236691f;
    const float w = r ? 0.07322326809171f : 0.42677648190829f;
    float arg = proj * sqrtf(2.0f * s) - s;
    arg = fminf(fmaxf(arg, -20.0f), 20.0f);
    outrow[64 + t] = expf(arg) * (sqrtf(w) / sqrtf(32.000001f));
  }
}

__global__ void k_anchors(const float* __restrict__ anchors, float* __restrict__ anchT) {
  const int d = threadIdx.x;  // 64 threads = 1 wave
  for (int p = 0; p < 16; p++) {
    const float v = anchors[p * 64 + d];
    const float n = sqrtf(wave_sum(v * v));
    anchT[d * 16 + p] = v / n;
  }
}

__global__ __launch_bounds__(256) void k_query(const int* __restrict__ indices,
                                               const float* __restrict__ mask,
                                               const float* __restrict__ embed,
                                               const float* __restrict__ anchT,
                                               const float* __restrict__ omega,
                                               float* __restrict__ qcomp) {
  const int b = blockIdx.x, t = threadIdx.x;
  __shared__ int sidx[L_SEQ];
  __shared__ float smask[L_SEQ];
  __shared__ float sx[256];
  if (t < L_SEQ) { sidx[t] = indices[b * L_SEQ + t]; smask[t] = mask[b * L_SEQ + t]; }
  __syncthreads();
  float acc = 0.f, msum = 0.f;
#pragma unroll 4
  for (int l = 0; l < L_SEQ; l++) {
    const float m = smask[l];
    msum += m;
    acc = fmaf(embed[(size_t)sidx[l] * D_EMB + t], m, acc);
  }
  const float q = acc / fmaxf(msum, 1.0f);
  const float ss = wave_sum(q * q);   // wave == head (64 dims)
  sx[t] = q / fmaxf(sqrtf(ss), 1e-4f);
  __syncthreads();
  slay_tail(sx, t, anchT, omega, qcomp + (size_t)b * CROW);
}

__global__ __launch_bounds__(256) void k_wrows(const int* __restrict__ labels,
                                               const int* __restrict__ negidx,
                                               const float* __restrict__ kern,
                                               const float* __restrict__ anchT,
                                               const float* __restrict__ omega,
                                               float* __restrict__ wcomp) {
  const int i = blockIdx.x, t = threadIdx.x;
  __shared__ float sx[256];
  int j;
  if (i < LBL_ROWS) { j = labels[i]; if (j < 0) j = 0; }
  else               { j = negidx[i - LBL_ROWS]; }
  const float x = kern[(size_t)t * NLAB + j];   // W[j][t] = kernel[t][j]
  const float ss = wave_sum(x * x);
  sx[t] = x / fmaxf(sqrtf(ss), 1e-4f);
  __syncthreads();
  slay_tail(sx, t, anchT, omega, wcomp + (size_t)i * CROW);
}

__global__ __launch_bounds__(256) void k_zero(float* __restrict__ p, int n) {
  const int i = blockIdx.x * 256 + threadIdx.x;
  if (i < n) p[i] = 0.f;
}

// neg partial sums, per-head separable: grid (16 qtiles, 64 wtiles, 4 heads), 128 thr.
// Block: 64 q x 32 w x one h. Thread: 4q x 4w. LDS rows hold this head's 80 k-values.
__global__ __launch_bounds__(128) void k_neg(const float* __restrict__ qcomp,
                                             const float* __restrict__ wcomp,
                                             float* __restrict__ negparts) {
  __shared__ float qt[64 * LST];
  __shared__ float wt[32 * LST];
  const int tid = threadIdx.x;
  const int qb0 = blockIdx.x * 64;
  const int wr0 = LBL_ROWS + blockIdx.y * 32;
  const int h = blockIdx.z;

  // stage 96 rows x 80 floats (this head's slice), 20 float4 per row
  for (int idx = tid; idx < 96 * 20; idx += 128) {
    const int row = idx / 20, c4 = idx % 20;
    int col, lcol;
    if (c4 < 4)       { col = h * 16 + c4 * 4;              lcol = c4 * 4; }
    else if (c4 < 12) { col = 64 + h * 32 + (c4 - 4) * 4;   lcol = 16 + (c4 - 4) * 4; }
    else              { col = 192 + h * 32 + (c4 - 12) * 4; lcol = 48 + (c4 - 12) * 4; }
    const bool isq = row < 64;
    const int grow = isq ? (qb0 + row) : (wr0 + row - 64);
    const float4 v = *(const float4*)((isq ? qcomp : wcomp) + (size_t)grow * CROW + col);
    float* dst = (isq ? qt + row * LST : wt + (row - 64) * LST) + lcol;
    dst[0] = v.x; dst[1] = v.y; dst[2] = v.z; dst[3] = v.w;
  }
  __syncthreads();

  const int qg = tid >> 3;   // 0..15 -> 4 q rows each
  const int wg = tid & 7;    // 0..7  -> 4 w rows each
  const float* qb = qt + (qg * 4) * LST;
  const float* wb = wt + (wg * 4) * LST;

  float pd[4][4] = {{0.f}}, pf[4][4] = {{0.f}};
  // poly: LDS cols [0,16)
#pragma unroll
  for (int kc = 0; kc < 8; kc++) {
    float2 qv[4], wv[4];
#pragma unroll
    for (int i = 0; i < 4; i++) qv[i] = *(const float2*)(qb + i * LST + 2 * kc);
#pragma unroll
    for (int j = 0; j < 4; j++) wv[j] = *(const float2*)(wb + j * LST + 2 * kc);
#pragma unroll
    for (int i = 0; i < 4; i++)
#pragma unroll
      for (int j = 0; j < 4; j++) {
        pd[i][j] = fmaf(qv[i].x, wv[j].x, pd[i][j]);
        pd[i][j] = fmaf(qv[i].y, wv[j].y, pd[i][j]);
      }
  }
  // prf (r0||r1 concatenated = p0+p1): LDS cols [16,80)
#pragma unroll 8
  for (int kc = 0; kc < 32; kc++) {
    float2 qv[4], wv[4];
#pragma unroll
    for (int i = 0; i < 4; i++) qv[i] = *(const float2*)(qb + i * LST + 16 + 2 * kc);
#pragma unroll
    for (int j = 0; j < 4; j++) wv[j] = *(const float2*)(wb + j * LST + 16 + 2 * kc);
#pragma unroll
    for (int i = 0; i < 4; i++)
#pragma unroll
      for (int j = 0; j < 4; j++) {
        pf[i][j] = fmaf(qv[i].x, wv[j].x, pf[i][j]);
        pf[i][j] = fmaf(qv[i].y, wv[j].y, pf[i][j]);
      }
  }

#pragma unroll
  for (int i = 0; i < 4; i++) {
    float acc = 0.f;
#pragma unroll
    for (int j = 0; j < 4; j++) acc += pd[i][j] * pf[i][j];
#pragma unroll
    for (int off = 1; off < 8; off <<= 1) acc += __shfl_xor(acc, off, 64);
    if (wg == 0) atomicAdd(&negparts[blockIdx.y * B_Q + qb0 + qg * 4 + i], acc);
  }
}

// pos scores: one thread per (pair, head). 128 blocks x 256 thr = 8192 pairs x 4 h.
__global__ __launch_bounds__(256) void k_pos(const float* __restrict__ qcomp,
                                             const float* __restrict__ wcomp,
                                             float* __restrict__ pos) {
  const int tid = threadIdx.x;
  const int g = blockIdx.x * 64 + (tid >> 2);  // pair
  const int h = tid & 3;
  const float* q = qcomp + (size_t)(g >> 3) * CROW;
  const float* w = wcomp + (size_t)g * CROW;
  float pd = 0.f, pf = 0.f;
#pragma unroll
  for (int c = 0; c < 4; c++) {
    const float4 qv = *(const float4*)(q + h * 16 + c * 4);
    const float4 wv = *(const float4*)(w + h * 16 + c * 4);
    pd += qv.x * wv.x + qv.y * wv.y + qv.z * wv.z + qv.w * wv.w;
  }
#pragma unroll
  for (int r = 0; r < 2; r++)
#pragma unroll
    for (int c = 0; c < 8; c++) {
      const float4 qv = *(const float4*)(q + 64 + r * 128 + h * 32 + c * 4);
      const float4 wv = *(const float4*)(w + 64 + r * 128 + h * 32 + c * 4);
      pf += qv.x * wv.x + qv.y * wv.y + qv.z * wv.z + qv.w * wv.w;
    }
  float sc = pd * pf;
  sc += __shfl_xor(sc, 1, 64);
  sc += __shfl_xor(sc, 2, 64);
  if (h == 0) pos[g] = sc;
}

__global__ __launch_bounds__(1024) void k_loss(const float* __restrict__ pos,
                                               const float* __restrict__ negparts,
                                               const float* __restrict__ lmask,
                                               float* __restrict__ out) {
  const int b = threadIdx.x;  // 1024
  float lp[8];
  float possum = 0.f;
#pragma unroll
  for (int k = 0; k < 8; k++) { lp[k] = pos[b * 8 + k]; possum += lp[k]; }
  float negsum = 0.f;
#pragma unroll 8
  for (int c = 0; c < 64; c++) negsum += negparts[c * B_Q + b];
  const float Z = possum + negsum + 2.056e-5f;  // + 2056 * 1e-8
  const float logZ = logf(Z);
  float local = 0.f, lsum = 0.f;
#pragma unroll
  for (int k = 0; k < 8; k++) {
    const float lm = lmask[b * 8 + k];
    local += lm * (logf(lp[k] + 1e-8f) - logZ);
    lsum += lm;
  }
  local = wave_sum(local);
  lsum = wave_sum(lsum);
  __shared__ float r1[16], r2[16];
  const int wid = b >> 6;
  if ((b & 63) == 0) { r1[wid] = local; r2[wid] = lsum; }
  __syncthreads();
  if (b == 0) {
    float t1 = 0.f, t2 = 0.f;
    for (int wv = 0; wv < 16; wv++) { t1 += r1[wv]; t2 += r2[wv]; }
    out[0] = -t1 / (t2 + 1e-6f);
  }
}

extern "C" void kernel_launch(void* const* d_in, const int* in_sizes, int n_in,
                              void* d_out, int out_size, void* d_ws, size_t ws_size,
                              hipStream_t stream) {
  const int* indices  = (const int*)d_in[0];
  const float* mask   = (const float*)d_in[1];
  const int* labels   = (const int*)d_in[2];
  const float* lmask  = (const float*)d_in[3];
  const int* negidx   = (const int*)d_in[4];
  const float* embed  = (const float*)d_in[5];
  const float* kern   = (const float*)d_in[6];
  const float* omega  = (const float*)d_in[7];
  const float* anchors= (const float*)d_in[8];
  float* out = (float*)d_out;

  float* ws = (float*)d_ws;
  float* anchT    = ws;                            // 1024
  float* qcomp    = anchT + 1024;                  // 1024*320
  float* wcomp    = qcomp + (size_t)B_Q * CROW;    // 10240*320
  float* pos      = wcomp + (size_t)W_ROWS * CROW; // 8192
  float* negparts = pos + LBL_ROWS;                // 64*1024

  k_anchors<<<1, 64, 0, stream>>>(anchors, anchT);
  k_query<<<B_Q, 256, 0, stream>>>(indices, mask, embed, anchT, omega, qcomp);
  k_wrows<<<W_ROWS, 256, 0, stream>>>(labels, negidx, kern, anchT, omega, wcomp);
  k_zero<<<(64 * B_Q + 255) / 256, 256, 0, stream>>>(negparts, 64 * B_Q);
  k_neg<<<dim3(16, 64, 4), 128, 0, stream>>>(qcomp, wcomp, negparts);
  k_pos<<<128, 256, 0, stream>>>(qcomp, wcomp, pos);
  k_loss<<<1, 1024, 0, stream>>>(pos, negparts, lmask, out);
}

// Round 3
// 361.836 us; speedup vs baseline: 1.5798x; 1.0123x over previous
//
#include <hip/hip_runtime.h>
#include <math.h>

#define B_Q 1024
#define L_SEQ 128
#define D_EMB 256
#define NLAB 131072
#define LBL_ROWS 8192
#define NEG_ROWS 2048
#define W_ROWS 10240
#define CROW 320   // compact row: 64 poly + 256 prf
#define LST 82     // k_neg LDS row stride
#define RPB 8      // k_wrows rows per block

__device__ __forceinline__ float wave_sum(float v) {
#pragma unroll
  for (int off = 32; off > 0; off >>= 1) v += __shfl_xor(v, off, 64);
  return v;
}

// sx: 256 per-head-normalized dims in LDS. t in [0,256). One compact row out.
__device__ __forceinline__ void slay_tail(const float* __restrict__ sx, int t,
                                          const float* __restrict__ anchT,
                                          const float* __restrict__ omega,
                                          float* __restrict__ outrow) {
  if (t < 64) {
    const int h = t >> 4, p = t & 15;
    const float* x = sx + h * 64;
    float d = 0.f;
#pragma unroll
    for (int dd = 0; dd < 64; dd++) d = fmaf(x[dd], anchT[dd * 16 + p], d);
    d = fminf(fmaxf(d, -1.0f), 1.0f);
    outrow[h * 16 + p] = d * d * 0.25f;
  }
  {
    const int r = t >> 7, h = (t >> 5) & 3;
    const float* x = sx + h * 64;
    const float* om = omega + (size_t)(t >> 5) * 2048 + (t & 31);
    float d = 0.f;
#pragma unroll
    for (int dd = 0; dd < 64; dd++) d = fmaf(x[dd], om[dd * 32], d);
    const float proj = d * 0.125f;
    const float s = r ? 1.70710592763316f : 0.29289307236691f;
    const float w = r ? 0.07322326809171f : 0.42677648190829f;
    float arg = proj * sqrtf(2.0f * s) - s;
    arg = fminf(fmaxf(arg, -20.0f), 20.0f);
    outrow[64 + t] = expf(arg) * (sqrtf(w) / sqrtf(32.000001f));
  }
}

// block 0: normalize+transpose anchors. blocks 1..256: zero negparts (64*1024).
__global__ __launch_bounds__(256) void k_prep(const float* __restrict__ anchors,
                                              float* __restrict__ anchT,
                                              float* __restrict__ negparts) {
  const int t = threadIdx.x;
  if (blockIdx.x == 0) {
    if (t < 64) {
      for (int p = 0; p < 16; p++) {
        const float v = anchors[p * 64 + t];
        const float n = sqrtf(wave_sum(v * v));
        anchT[t * 16 + p] = v / n;
      }
    }
  } else {
    negparts[(blockIdx.x - 1) * 256 + t] = 0.f;
  }
}

__global__ __launch_bounds__(256) void k_query(const int* __restrict__ indices,
                                               const float* __restrict__ mask,
                                               const float* __restrict__ embed,
                                               const float* __restrict__ anchT,
                                               const float* __restrict__ omega,
                                               float* __restrict__ qcomp) {
  const int b = blockIdx.x, t = threadIdx.x;
  const int wv = t >> 6, ln = t & 63;
  __shared__ int sidx[L_SEQ];
  __shared__ float smask[L_SEQ];
  __shared__ float4 spart[256];
  __shared__ float smsum[4];
  __shared__ float sx[256];
  if (t < L_SEQ) { sidx[t] = indices[b * L_SEQ + t]; smask[t] = mask[b * L_SEQ + t]; }
  __syncthreads();
  float4 acc = {0.f, 0.f, 0.f, 0.f};
  float msum = 0.f;
#pragma unroll 8
  for (int l = wv * 32; l < wv * 32 + 32; l++) {
    const float m = smask[l];
    msum += m;
    const float4 e = *(const float4*)(embed + (size_t)sidx[l] * D_EMB + ln * 4);
    acc.x = fmaf(e.x, m, acc.x); acc.y = fmaf(e.y, m, acc.y);
    acc.z = fmaf(e.z, m, acc.z); acc.w = fmaf(e.w, m, acc.w);
  }
  spart[wv * 64 + ln] = acc;
  if (ln == 0) smsum[wv] = msum;  // msum uniform across the wave
  __syncthreads();
  const float* spf = (const float*)spart;
  float q = spf[t] + spf[256 + t] + spf[512 + t] + spf[768 + t];
  const float mt = smsum[0] + smsum[1] + smsum[2] + smsum[3];
  q /= fmaxf(mt, 1.0f);
  const float ss = wave_sum(q * q);  // wave == head
  sx[t] = q / fmaxf(sqrtf(ss), 1e-4f);
  __syncthreads();
  slay_tail(sx, t, anchT, omega, qcomp + (size_t)b * CROW);
}

// 8 rows per block: batched gather, LDS normalize, omega loaded once per 8 rows.
__global__ __launch_bounds__(256) void k_wrows(const int* __restrict__ labels,
                                               const int* __restrict__ negidx,
                                               const float* __restrict__ kern,
                                               const float* __restrict__ anchT,
                                               const float* __restrict__ omega,
                                               float* __restrict__ wcomp) {
  __shared__ int sj[RPB];
  __shared__ float sx[RPB * 256];
  __shared__ float snorm[RPB * 4];
  const int tid = threadIdx.x;
  const int i0 = blockIdx.x * RPB;

  if (tid < RPB) {
    const int i = i0 + tid;
    int j;
    if (i < LBL_ROWS) { j = labels[i]; if (j < 0) j = 0; }
    else               { j = negidx[i - LBL_ROWS]; }
    sj[tid] = j;
  }
  __syncthreads();

  // gather 8 columns of kern (8 independent 64-line gathers in flight)
#pragma unroll
  for (int k = 0; k < RPB; k++) {
    const int idx = k * 256 + tid;
    sx[idx] = kern[(size_t)(idx & 255) * NLAB + sj[idx >> 8]];
  }
  __syncthreads();

  // per-(row,head) norms: 32 threads/row, 8 elems each, octet shuffle-reduce
  {
    const int row = tid >> 5, sub = tid & 31;
    const float* xp = sx + row * 256 + sub * 8;
    float ssum = 0.f;
#pragma unroll
    for (int e = 0; e < 8; e++) ssum = fmaf(xp[e], xp[e], ssum);
    ssum += __shfl_xor(ssum, 1, 64);
    ssum += __shfl_xor(ssum, 2, 64);
    ssum += __shfl_xor(ssum, 4, 64);
    if ((sub & 7) == 0) snorm[row * 4 + (sub >> 3)] = fmaxf(sqrtf(ssum), 1e-4f);
  }
  __syncthreads();
#pragma unroll
  for (int k = 0; k < RPB; k++) {
    const int idx = k * 256 + tid;
    sx[idx] /= snorm[(idx >> 8) * 4 + ((idx >> 6) & 3)];
  }
  __syncthreads();

  // prf: thread = (r,h,m); omega element loaded once, used for 8 rows
  {
    const int h = (tid >> 5) & 3, r = tid >> 7;
    const float* om = omega + (size_t)(tid >> 5) * 2048 + (tid & 31);
    float acc[RPB];
#pragma unroll
    for (int row = 0; row < RPB; row++) acc[row] = 0.f;
#pragma unroll
    for (int dd = 0; dd < 64; dd += 2) {
      const float o0 = om[dd * 32], o1 = om[dd * 32 + 32];
#pragma unroll
      for (int row = 0; row < RPB; row++) {
        const float2 xv = *(const float2*)(sx + row * 256 + h * 64 + dd);
        acc[row] = fmaf(xv.x, o0, fmaf(xv.y, o1, acc[row]));
      }
    }
    const float s = r ? 1.70710592763316f : 0.29289307236691f;
    const float w = r ? 0.07322326809171f : 0.42677648190829f;
    const float sc = sqrtf(2.0f * s);
    const float outs = sqrtf(w) / sqrtf(32.000001f);
#pragma unroll
    for (int row = 0; row < RPB; row++) {
      float arg = acc[row] * 0.125f * sc - s;
      arg = fminf(fmaxf(arg, -20.0f), 20.0f);
      wcomp[(size_t)(i0 + row) * CROW + 64 + tid] = expf(arg) * outs;
    }
  }

  // poly: thread = (hp, rowpair); 2 rows each
  {
    const int hp = tid & 63, rp = tid >> 6;
    const int h = hp >> 4, p = hp & 15;
    const float* x0 = sx + (rp * 2) * 256 + h * 64;
    const float* x1 = x0 + 256;
    float d0 = 0.f, d1 = 0.f;
#pragma unroll
    for (int dd = 0; dd < 64; dd++) {
      const float a = anchT[dd * 16 + p];
      d0 = fmaf(x0[dd], a, d0);
      d1 = fmaf(x1[dd], a, d1);
    }
    d0 = fminf(fmaxf(d0, -1.0f), 1.0f);
    d1 = fminf(fmaxf(d1, -1.0f), 1.0f);
    wcomp[(size_t)(i0 + rp * 2) * CROW + h * 16 + p]     = d0 * d0 * 0.25f;
    wcomp[(size_t)(i0 + rp * 2 + 1) * CROW + h * 16 + p] = d1 * d1 * 0.25f;
  }
}

// neg partial sums: grid (16 qtiles, 64 wtiles, 4 heads), 128 thr.
__global__ __launch_bounds__(128) void k_neg(const float* __restrict__ qcomp,
                                             const float* __restrict__ wcomp,
                                             float* __restrict__ negparts) {
  __shared__ float qt[64 * LST];
  __shared__ float wt[32 * LST];
  const int tid = threadIdx.x;
  const int qb0 = blockIdx.x * 64;
  const int wr0 = LBL_ROWS + blockIdx.y * 32;
  const int h = blockIdx.z;

  for (int idx = tid; idx < 96 * 20; idx += 128) {
    const int row = idx / 20, c4 = idx % 20;
    int col, lcol;
    if (c4 < 4)       { col = h * 16 + c4 * 4;              lcol = c4 * 4; }
    else if (c4 < 12) { col = 64 + h * 32 + (c4 - 4) * 4;   lcol = 16 + (c4 - 4) * 4; }
    else              { col = 192 + h * 32 + (c4 - 12) * 4; lcol = 48 + (c4 - 12) * 4; }
    const bool isq = row < 64;
    const int grow = isq ? (qb0 + row) : (wr0 + row - 64);
    const float4 v = *(const float4*)((isq ? qcomp : wcomp) + (size_t)grow * CROW + col);
    float* dst = (isq ? qt + row * LST : wt + (row - 64) * LST) + lcol;
    dst[0] = v.x; dst[1] = v.y; dst[2] = v.z; dst[3] = v.w;
  }
  __syncthreads();

  const int qg = tid >> 3;
  const int wg = tid & 7;
  const float* qb = qt + (qg * 4) * LST;
  const float* wb = wt + (wg * 4) * LST;

  float pd[4][4] = {{0.f}}, pf[4][4] = {{0.f}};
#pragma unroll
  for (int kc = 0; kc < 8; kc++) {
    float2 qv[4], wv[4];
#pragma unroll
    for (int i = 0; i < 4; i++) qv[i] = *(const float2*)(qb + i * LST + 2 * kc);
#pragma unroll
    for (int j = 0; j < 4; j++) wv[j] = *(const float2*)(wb + j * LST + 2 * kc);
#pragma unroll
    for (int i = 0; i < 4; i++)
#pragma unroll
      for (int j = 0; j < 4; j++) {
        pd[i][j] = fmaf(qv[i].x, wv[j].x, pd[i][j]);
        pd[i][j] = fmaf(qv[i].y, wv[j].y, pd[i][j]);
      }
  }
#pragma unroll 8
  for (int kc = 0; kc < 32; kc++) {
    float2 qv[4], wv[4];
#pragma unroll
    for (int i = 0; i < 4; i++) qv[i] = *(const float2*)(qb + i * LST + 16 + 2 * kc);
#pragma unroll
    for (int j = 0; j < 4; j++) wv[j] = *(const float2*)(wb + j * LST + 16 + 2 * kc);
#pragma unroll
    for (int i = 0; i < 4; i++)
#pragma unroll
      for (int j = 0; j < 4; j++) {
        pf[i][j] = fmaf(qv[i].x, wv[j].x, pf[i][j]);
        pf[i][j] = fmaf(qv[i].y, wv[j].y, pf[i][j]);
      }
  }

#pragma unroll
  for (int i = 0; i < 4; i++) {
    float acc = 0.f;
#pragma unroll
    for (int j = 0; j < 4; j++) acc += pd[i][j] * pf[i][j];
#pragma unroll
    for (int off = 1; off < 8; off <<= 1) acc += __shfl_xor(acc, off, 64);
    if (wg == 0) atomicAdd(&negparts[blockIdx.y * B_Q + qb0 + qg * 4 + i], acc);
  }
}

__global__ __launch_bounds__(256) void k_pos(const float* __restrict__ qcomp,
                                             const float* __restrict__ wcomp,
                                             float* __restrict__ pos) {
  const int tid = threadIdx.x;
  const int g = blockIdx.x * 64 + (tid >> 2);
  const int h = tid & 3;
  const float* q = qcomp + (size_t)(g >> 3) * CROW;
  const float* w = wcomp + (size_t)g * CROW;
  float pd = 0.f, pf = 0.f;
#pragma unroll
  for (int c = 0; c < 4; c++) {
    const float4 qv = *(const float4*)(q + h * 16 + c * 4);
    const float4 wv = *(const float4*)(w + h * 16 + c * 4);
    pd += qv.x * wv.x + qv.y * wv.y + qv.z * wv.z + qv.w * wv.w;
  }
#pragma unroll
  for (int r = 0; r < 2; r++)
#pragma unroll
    for (int c = 0; c < 8; c++) {
      const float4 qv = *(const float4*)(q + 64 + r * 128 + h * 32 + c * 4);
      const float4 wv = *(const float4*)(w + 64 + r * 128 + h * 32 + c * 4);
      pf += qv.x * wv.x + qv.y * wv.y + qv.z * wv.z + qv.w * wv.w;
    }
  float sc = pd * pf;
  sc += __shfl_xor(sc, 1, 64);
  sc += __shfl_xor(sc, 2, 64);
  if (h == 0) pos[g] = sc;
}

__global__ __launch_bounds__(1024) void k_loss(const float* __restrict__ pos,
                                               const float* __restrict__ negparts,
                                               const float* __restrict__ lmask,
                                               float* __restrict__ out) {
  const int b = threadIdx.x;
  float lp[8];
  float possum = 0.f;
#pragma unroll
  for (int k = 0; k < 8; k++) { lp[k] = pos[b * 8 + k]; possum += lp[k]; }
  float negsum = 0.f;
#pragma unroll 8
  for (int c = 0; c < 64; c++) negsum += negparts[c * B_Q + b];
  const float Z = possum + negsum + 2.056e-5f;
  const float logZ = logf(Z);
  float local = 0.f, lsum = 0.f;
#pragma unroll
  for (int k = 0; k < 8; k++) {
    const float lm = lmask[b * 8 + k];
    local += lm * (logf(lp[k] + 1e-8f) - logZ);
    lsum += lm;
  }
  local = wave_sum(local);
  lsum = wave_sum(lsum);
  __shared__ float r1[16], r2[16];
  const int wid = b >> 6;
  if ((b & 63) == 0) { r1[wid] = local; r2[wid] = lsum; }
  __syncthreads();
  if (b == 0) {
    float t1 = 0.f, t2 = 0.f;
    for (int wv = 0; wv < 16; wv++) { t1 += r1[wv]; t2 += r2[wv]; }
    out[0] = -t1 / (t2 + 1e-6f);
  }
}

extern "C" void kernel_launch(void* const* d_in, const int* in_sizes, int n_in,
                              void* d_out, int out_size, void* d_ws, size_t ws_size,
                              hipStream_t stream) {
  const int* indices  = (const int*)d_in[0];
  const float* mask   = (const float*)d_in[1];
  const int* labels   = (const int*)d_in[2];
  const float* lmask  = (const float*)d_in[3];
  const int* negidx   = (const int*)d_in[4];
  const float* embed  = (const float*)d_in[5];
  const float* kern   = (const float*)d_in[6];
  const float* omega  = (const float*)d_in[7];
  const float* anchors= (const float*)d_in[8];
  float* out = (float*)d_out;

  float* ws = (float*)d_ws;
  float* anchT    = ws;                            // 1024
  float* qcomp    = anchT + 1024;                  // 1024*320
  float* wcomp    = qcomp + (size_t)B_Q * CROW;    // 10240*320
  float* pos      = wcomp + (size_t)W_ROWS * CROW; // 8192
  float* negparts = pos + LBL_ROWS;                // 64*1024

  k_prep<<<257, 256, 0, stream>>>(anchors, anchT, negparts);
  k_query<<<B_Q, 256, 0, stream>>>(indices, mask, embed, anchT, omega, qcomp);
  k_wrows<<<W_ROWS / RPB, 256, 0, stream>>>(labels, negidx, kern, anchT, omega, wcomp);
  k_neg<<<dim3(16, 64, 4), 128, 0, stream>>>(qcomp, wcomp, negparts);
  k_pos<<<128, 256, 0, stream>>>(qcomp, wcomp, pos);
  k_loss<<<1, 1024, 0, stream>>>(pos, negparts, lmask, out);
}